// Round 7
// baseline (38.869 us; speedup 1.0000x reference)
//
#include <hip/hip_runtime.h>

#define POOL 7
#define NUM_ROIS 512
#define H_IMG 128
#define W_IMG 128
#define C_IMG 1024
#define NITEMS (NUM_ROIS * POOL)   // 3584 work items = (roi, py) rows
#define IPX (NITEMS / 8)           // 448 items per XCD chunk

typedef float f32x4 __attribute__((ext_vector_type(4)));

// ---------------------------------------------------------------------------
// Pre-pass: counting-sort the 3584 (roi,py) work items by source image row
// ay0 = y + y0 (128 bins, parallel Hillis-Steele scan). Rewrites perm[]
// entirely every call; within-bin order is atomic-timing dependent but
// harmless (each item writes a disjoint output slice).
// ---------------------------------------------------------------------------
__device__ __forceinline__ int item_key(const int4 roi, int py) {
    const float hf = (float)roi.w;                       // h
    float ysf = ((float)py + 0.5f) * hf / 7.0f - 0.5f;
    ysf = fminf(fmaxf(ysf, 0.0f), hf - 1.0f);
    return roi.y + (int)floorf(ysf);                     // ay0 in [0,127]
}

__global__ __launch_bounds__(1024) void build_perm_kernel(
    const int* __restrict__ rois, int* __restrict__ perm)
{
    __shared__ int hist[128];
    __shared__ int scan[128];
    const int tid = threadIdx.x;
    if (tid < 128) hist[tid] = 0;
    __syncthreads();

    for (int i = tid; i < NITEMS; i += 1024) {
        const int r = i / POOL, py = i - r * POOL;
        const int4 roi = ((const int4*)rois)[r];
        atomicAdd(&hist[item_key(roi, py)], 1);
    }
    __syncthreads();

    if (tid < 128) scan[tid] = hist[tid];
    __syncthreads();
    #pragma unroll
    for (int off = 1; off < 128; off <<= 1) {
        int v = 0;
        if (tid < 128 && tid >= off) v = scan[tid - off];
        __syncthreads();
        if (tid < 128) scan[tid] += v;
        __syncthreads();
    }
    if (tid < 128) hist[tid] = scan[tid] - hist[tid];   // exclusive cursor
    __syncthreads();

    for (int i = tid; i < NITEMS; i += 1024) {
        const int r = i / POOL, py = i - r * POOL;
        const int4 roi = ((const int4*)rois)[r];
        const int pos = atomicAdd(&hist[item_key(roi, py)], 1);
        perm[pos] = i;
    }
}

// ---------------------------------------------------------------------------
// Main kernel: TWO (roi,py) items per 256-thread block, software-pipelined:
//   issue item0 x28 loads, issue item1 top x14, [fence],
//   consume item0 (stores), issue item1 bottom x14, [fence], consume item1.
// Per wave ~1 full latency exposure per 2 items; ~42 KB in flight.
// __launch_bounds__(256,2): VGPR cap 256 for the ~170 live f32x4 regs.
// ---------------------------------------------------------------------------
__global__ __launch_bounds__(256, 2) void roi_pool_row2_kernel(
    const float* __restrict__ img,   // (H, W, C)
    const int*   __restrict__ rois,  // (R, 4) as (x, y, w, h)
    const int*   __restrict__ perm,  // (NITEMS) sorted work ids
    float*       __restrict__ out)   // (R, P, P, C)
{
    const int bid = blockIdx.x;                       // 0..1791
    const int s   = (bid & 7) * IPX + ((bid >> 3) << 1);
    const int i0  = perm[s];
    const int i1  = perm[s + 1];
    const int t   = threadIdx.x;                      // 0..255

    // ---------------- setup item 0 ----------------
    const int r0  = i0 / POOL, py0 = i0 - r0 * POOL;
    const int4 roi0 = ((const int4*)rois)[r0];
    const float hf0 = (float)roi0.w, wf0 = (float)roi0.z;
    float ys0 = ((float)py0 + 0.5f) * hf0 / 7.0f - 0.5f;
    ys0 = fminf(fmaxf(ys0, 0.0f), hf0 - 1.0f);
    const int   y00 = (int)floorf(ys0);
    const int   y01 = min(y00 + 1, roi0.w - 1);
    const float fy0 = ys0 - (float)y00;
    const float gy0 = 1.0f - fy0;
    const f32x4* __restrict__ r0row0 =
        (const f32x4*)(img + (size_t)(roi0.y + y00) * W_IMG * C_IMG);
    const f32x4* __restrict__ r0row1 =
        (const f32x4*)(img + (size_t)(roi0.y + y01) * W_IMG * C_IMG);
    int ax00[POOL], ax01[POOL]; float fx0[POOL];
    #pragma unroll
    for (int px = 0; px < POOL; ++px) {
        float xs = ((float)px + 0.5f) * wf0 / 7.0f - 0.5f;
        xs = fminf(fmaxf(xs, 0.0f), wf0 - 1.0f);
        const int x0 = (int)floorf(xs);
        const int x1 = min(x0 + 1, roi0.z - 1);
        fx0[px] = xs - (float)x0;
        ax00[px] = roi0.x + x0;
        ax01[px] = roi0.x + x1;
    }

    // ---------------- setup item 1 ----------------
    const int r1  = i1 / POOL, py1 = i1 - r1 * POOL;
    const int4 roi1 = ((const int4*)rois)[r1];
    const float hf1 = (float)roi1.w, wf1 = (float)roi1.z;
    float ys1 = ((float)py1 + 0.5f) * hf1 / 7.0f - 0.5f;
    ys1 = fminf(fmaxf(ys1, 0.0f), hf1 - 1.0f);
    const int   y10 = (int)floorf(ys1);
    const int   y11 = min(y10 + 1, roi1.w - 1);
    const float fy1 = ys1 - (float)y10;
    const float gy1 = 1.0f - fy1;
    const f32x4* __restrict__ r1row0 =
        (const f32x4*)(img + (size_t)(roi1.y + y10) * W_IMG * C_IMG);
    const f32x4* __restrict__ r1row1 =
        (const f32x4*)(img + (size_t)(roi1.y + y11) * W_IMG * C_IMG);
    int ax10[POOL], ax11[POOL]; float fx1[POOL];
    #pragma unroll
    for (int px = 0; px < POOL; ++px) {
        float xs = ((float)px + 0.5f) * wf1 / 7.0f - 0.5f;
        xs = fminf(fmaxf(xs, 0.0f), wf1 - 1.0f);
        const int x0 = (int)floorf(xs);
        const int x1 = min(x0 + 1, roi1.z - 1);
        fx1[px] = xs - (float)x0;
        ax10[px] = roi1.x + x0;
        ax11[px] = roi1.x + x1;
    }

    // ---------------- issue phase ----------------
    f32x4 A0[POOL], B0[POOL], C0[POOL], D0[POOL];
    #pragma unroll
    for (int px = 0; px < POOL; ++px) {
        A0[px] = r0row0[(ax00[px] << 8) + t];
        B0[px] = r0row0[(ax01[px] << 8) + t];
    }
    #pragma unroll
    for (int px = 0; px < POOL; ++px) {
        C0[px] = r0row1[(ax00[px] << 8) + t];
        D0[px] = r0row1[(ax01[px] << 8) + t];
    }
    f32x4 A1[POOL], B1[POOL];
    #pragma unroll
    for (int px = 0; px < POOL; ++px) {
        A1[px] = r1row0[(ax10[px] << 8) + t];
        B1[px] = r1row0[(ax11[px] << 8) + t];
    }
    // Fence: nothing crosses — all 42 loads stay issued before first consume.
    __builtin_amdgcn_sched_barrier(0);

    // ---------------- consume item 0 ----------------
    f32x4* __restrict__ po0 =
        (f32x4*)(out + ((size_t)(r0 * 49 + py0 * 7)) * C_IMG);
    #pragma unroll
    for (int px = 0; px < POOL; ++px) {
        const float f = fx0[px], g = 1.0f - f;
        f32x4 top = A0[px] * g + B0[px] * f;
        f32x4 bot = C0[px] * g + D0[px] * f;
        f32x4 o   = top * gy0 + bot * fy0;
        __builtin_nontemporal_store(o, &po0[(px << 8) + t]);
    }

    // ---------------- issue item 1 bottom ----------------
    f32x4 C1[POOL], D1[POOL];
    #pragma unroll
    for (int px = 0; px < POOL; ++px) {
        C1[px] = r1row1[(ax10[px] << 8) + t];
        D1[px] = r1row1[(ax11[px] << 8) + t];
    }
    __builtin_amdgcn_sched_barrier(0);

    // ---------------- consume item 1 ----------------
    f32x4* __restrict__ po1 =
        (f32x4*)(out + ((size_t)(r1 * 49 + py1 * 7)) * C_IMG);
    #pragma unroll
    for (int px = 0; px < POOL; ++px) {
        const float f = fx1[px], g = 1.0f - f;
        f32x4 top = A1[px] * g + B1[px] * f;
        f32x4 bot = C1[px] * g + D1[px] * f;
        f32x4 o   = top * gy1 + bot * fy1;
        __builtin_nontemporal_store(o, &po1[(px << 8) + t]);
    }
}

extern "C" void kernel_launch(void* const* d_in, const int* in_sizes, int n_in,
                              void* d_out, int out_size, void* d_ws, size_t ws_size,
                              hipStream_t stream) {
    const float* img  = (const float*)d_in[0];   // (1,128,128,1024) fp32
    const int*   rois = (const int*)d_in[1];     // (1,512,4) int32
    float*       out  = (float*)d_out;           // (1,512,7,7,1024) fp32
    int*         perm = (int*)d_ws;              // NITEMS ints of scratch

    build_perm_kernel<<<1, 1024, 0, stream>>>(rois, perm);
    roi_pool_row2_kernel<<<NITEMS / 2, 256, 0, stream>>>(img, rois, perm, out);
}

// Round 8
// 38.105 us; speedup vs baseline: 1.0201x; 1.0201x over previous
//
#include <hip/hip_runtime.h>

#define POOL 7
#define NUM_ROIS 512
#define H_IMG 128
#define W_IMG 128
#define C_IMG 1024
#define NITEMS (NUM_ROIS * POOL)   // 3584 work items = (roi, py) rows

typedef float f32x4 __attribute__((ext_vector_type(4)));

// ---------------------------------------------------------------------------
// Pre-pass: counting-sort the 3584 (roi,py) work items by source image row
// ay0 = y + y0 (128 bins). Scan done by wave 0 via shuffles — no barriers
// inside the scan (the old 7-step LDS scan cost 14 __syncthreads).
// Rewrites perm[] entirely every call; within-bin order is atomic-timing
// dependent but harmless (each item writes a disjoint output slice).
// ---------------------------------------------------------------------------
__device__ __forceinline__ int item_key(const int4 roi, int py) {
    const float hf = (float)roi.w;                       // h
    float ysf = ((float)py + 0.5f) * hf / 7.0f - 0.5f;
    ysf = fminf(fmaxf(ysf, 0.0f), hf - 1.0f);
    return roi.y + (int)floorf(ysf);                     // ay0 in [0,127]
}

__global__ __launch_bounds__(1024) void build_perm_kernel(
    const int* __restrict__ rois, int* __restrict__ perm)
{
    __shared__ int hist[128];
    const int tid = threadIdx.x;
    if (tid < 128) hist[tid] = 0;
    __syncthreads();

    for (int i = tid; i < NITEMS; i += 1024) {
        const int r = i / POOL, py = i - r * POOL;
        const int4 roi = ((const int4*)rois)[r];
        atomicAdd(&hist[item_key(roi, py)], 1);
    }
    __syncthreads();

    // Exclusive scan of the 128 bins by wave 0 only: lane l owns bins
    // {2l, 2l+1}; inclusive shuffle-scan of pair sums, then per-bin fixup.
    if (tid < 64) {
        const int v0 = hist[2 * tid];
        const int v1 = hist[2 * tid + 1];
        int s = v0 + v1;
        int inc = s;
        #pragma unroll
        for (int off = 1; off < 64; off <<= 1) {
            const int u = __shfl_up(inc, off, 64);
            if (tid >= off) inc += u;
        }
        const int excl_pair = inc - s;          // sum of bins < 2l
        hist[2 * tid]     = excl_pair;          // cursor for bin 2l
        hist[2 * tid + 1] = excl_pair + v0;     // cursor for bin 2l+1
    }
    __syncthreads();

    for (int i = tid; i < NITEMS; i += 1024) {
        const int r = i / POOL, py = i - r * POOL;
        const int4 roi = ((const int4*)rois)[r];
        const int pos = atomicAdd(&hist[item_key(roi, py)], 1);
        perm[pos] = i;
    }
}

// ---------------------------------------------------------------------------
// Main kernel: one 256-thread block per (roi, py) output row, work order
// from perm so each XCD streams a contiguous y-slice. Normal (write-back)
// stores this round: with sort-localized reads, the output stream passing
// through L2 should aggregate into large HBM write bursts (fillBuffer gets
// 6.7 TB/s this way); NT 1KB scattered bursts are the suspected write-path
// inefficiency. Watch FETCH_SIZE: >100MB means image got evicted — revert.
// ---------------------------------------------------------------------------
__global__ __launch_bounds__(256) void roi_pool_row_kernel(
    const float* __restrict__ img,   // (H, W, C)
    const int*   __restrict__ rois,  // (R, 4) as (x, y, w, h)
    const int*   __restrict__ perm,  // (NITEMS) sorted work ids
    float*       __restrict__ out)   // (R, P, P, C)
{
    const int bid  = blockIdx.x;
    const int swz  = (bid & 7) * (NITEMS / 8) + (bid >> 3);
    const int item = perm[swz];
    const int r    = item / POOL;
    const int py   = item - r * POOL;

    const int4 roi = ((const int4*)rois)[r];
    const int x = roi.x, y = roi.y, w = roi.z, h = roi.w;
    const float hf = (float)h, wf = (float)w;

    // y interpolation (same fp32 expression order as reference)
    float ysf = ((float)py + 0.5f) * hf / 7.0f - 0.5f;
    ysf = fminf(fmaxf(ysf, 0.0f), hf - 1.0f);
    const int   y0 = (int)floorf(ysf);
    const int   y1 = min(y0 + 1, h - 1);
    const float fy = ysf - (float)y0;
    const float gy = 1.0f - fy;

    const f32x4* __restrict__ row0 =
        (const f32x4*)(img + (size_t)(y + y0) * W_IMG * C_IMG);
    const f32x4* __restrict__ row1 =
        (const f32x4*)(img + (size_t)(y + y1) * W_IMG * C_IMG);

    // x interpolation for all 7 px
    int   ax0[POOL], ax1[POOL];
    float fx[POOL];
    #pragma unroll
    for (int px = 0; px < POOL; ++px) {
        float xsf = ((float)px + 0.5f) * wf / 7.0f - 0.5f;
        xsf = fminf(fmaxf(xsf, 0.0f), wf - 1.0f);
        const int x0 = (int)floorf(xsf);
        const int x1 = min(x0 + 1, w - 1);
        fx[px]  = xsf - (float)x0;
        ax0[px] = x + x0;
        ax1[px] = x + x1;
    }

    const int t = threadIdx.x;   // 0..255 ; C/4 == 256 exactly

    f32x4 A[POOL], B[POOL], C_[POOL], D[POOL];
    #pragma unroll
    for (int px = 0; px < POOL; ++px) {
        A[px]  = row0[(ax0[px] << 8) + t];
        B[px]  = row0[(ax1[px] << 8) + t];
    }
    #pragma unroll
    for (int px = 0; px < POOL; ++px) {
        C_[px] = row1[(ax0[px] << 8) + t];
        D[px]  = row1[(ax1[px] << 8) + t];
    }

    f32x4* __restrict__ po =
        (f32x4*)(out + ((size_t)(r * 49 + py * 7)) * C_IMG);

    #pragma unroll
    for (int px = 0; px < POOL; ++px) {
        const float f = fx[px], g = 1.0f - f;
        f32x4 top = A[px]  * g + B[px] * f;
        f32x4 bot = C_[px] * g + D[px] * f;
        f32x4 o   = top * gy + bot * fy;
        po[(px << 8) + t] = o;   // normal store: L2 write-back aggregation
    }
}

extern "C" void kernel_launch(void* const* d_in, const int* in_sizes, int n_in,
                              void* d_out, int out_size, void* d_ws, size_t ws_size,
                              hipStream_t stream) {
    const float* img  = (const float*)d_in[0];   // (1,128,128,1024) fp32
    const int*   rois = (const int*)d_in[1];     // (1,512,4) int32
    float*       out  = (float*)d_out;           // (1,512,7,7,1024) fp32
    int*         perm = (int*)d_ws;              // NITEMS ints of scratch

    build_perm_kernel<<<1, 1024, 0, stream>>>(rois, perm);
    roi_pool_row_kernel<<<NITEMS, 256, 0, stream>>>(img, rois, perm, out);
}